// Round 3
// baseline (16.208 us; speedup 1.0000x reference)
//
#include <hip/hip_runtime.h>

// VocabParallelEmbeddingWithTopping: per-token routed embedding gather.
// out[t, :] = (wi[t] == -1 ? base_weight[id[t], :] : delta_weights[wi[t], id[t], :])
//
// N = 8192 tokens, D = 1024 fp32 (4 KiB rows).
// One WAVE per token: 64 lanes x 4 x float4 = 4096 B. Blocks of 256 threads
// handle 4 tokens; grid = N/4 = 2048. Loads issued 4-deep before stores for
// in-wave memory-level parallelism; nontemporal to skip L2 pollution
// (64 MiB streamed once vs 32 MiB aggregate L2).
//
// NOTE: __builtin_nontemporal_* requires a clang native vector type, not
// HIP_vector_type (float4) — use ext_vector_type(4).

static constexpr int kVocab    = 32000;
static constexpr int kEmbedDim = 1024;

typedef float f32x4 __attribute__((ext_vector_type(4)));

__global__ __launch_bounds__(256) void routed_embed_kernel(
    const int* __restrict__ input_ids,
    const int* __restrict__ weight_indices,
    const float* __restrict__ base_weight,
    const float* __restrict__ delta_weights,
    float* __restrict__ out) {
    const int wave = threadIdx.x >> 6;
    const int lane = threadIdx.x & 63;
    const int t    = blockIdx.x * 4 + wave;

    const int id = input_ids[t];       // wave-uniform
    const int wi = weight_indices[t];  // wave-uniform

    const float* src = (wi < 0)
        ? base_weight + (size_t)id * kEmbedDim
        : delta_weights + ((size_t)wi * kVocab + (size_t)id) * kEmbedDim;

    const f32x4* __restrict__ s4 = reinterpret_cast<const f32x4*>(src);
    f32x4* __restrict__ o4 =
        reinterpret_cast<f32x4*>(out + (size_t)t * kEmbedDim);

    // Row = 256 float4; this wave's lane covers 4 of them, 64 apart.
    f32x4 v0 = __builtin_nontemporal_load(&s4[lane]);
    f32x4 v1 = __builtin_nontemporal_load(&s4[lane + 64]);
    f32x4 v2 = __builtin_nontemporal_load(&s4[lane + 128]);
    f32x4 v3 = __builtin_nontemporal_load(&s4[lane + 192]);

    __builtin_nontemporal_store(v0, &o4[lane]);
    __builtin_nontemporal_store(v1, &o4[lane + 64]);
    __builtin_nontemporal_store(v2, &o4[lane + 128]);
    __builtin_nontemporal_store(v3, &o4[lane + 192]);
}

extern "C" void kernel_launch(void* const* d_in, const int* in_sizes, int n_in,
                              void* d_out, int out_size, void* d_ws, size_t ws_size,
                              hipStream_t stream) {
    const int*   input_ids      = (const int*)d_in[0];
    const int*   weight_indices = (const int*)d_in[1];
    const float* base_weight    = (const float*)d_in[2];
    const float* delta_weights  = (const float*)d_in[3];
    float*       out            = (float*)d_out;

    const int num_tokens = in_sizes[0];  // 8192, divisible by 4
    const int grid       = num_tokens / 4;

    routed_embed_kernel<<<grid, 256, 0, stream>>>(
        input_ids, weight_indices, base_weight, delta_weights, out);
}

// Round 4
// 14.300 us; speedup vs baseline: 1.1334x; 1.1334x over previous
//
#include <hip/hip_runtime.h>

// VocabParallelEmbeddingWithTopping: per-token routed embedding gather.
// out[t, :] = (wi[t] == -1 ? base_weight[id[t], :] : delta_weights[wi[t], id[t], :])
//
// N = 8192 tokens, D = 1024 fp32 (4 KiB rows).
// One wave handles 4 tokens: indices fetched as one int4 pair, then all
// 16 row loads (4 rows x 4 float4/lane) issue before any store -> 16 KiB
// of in-flight reads per wave. Grid = 8192/16 = 512 blocks x 256 threads
// (2048 waves, 8/CU). Stores are nontemporal (out never re-read); row
// loads stay cached (duplicates negligible; nt was neutral in R2).

static constexpr int kVocab    = 32000;
static constexpr int kEmbedDim = 1024;

typedef float f32x4 __attribute__((ext_vector_type(4)));
typedef int   i32x4 __attribute__((ext_vector_type(4)));

__global__ __launch_bounds__(256) void routed_embed_kernel(
    const int* __restrict__ input_ids,
    const int* __restrict__ weight_indices,
    const float* __restrict__ base_weight,
    const float* __restrict__ delta_weights,
    float* __restrict__ out) {
    const int wave = threadIdx.x >> 6;
    const int lane = threadIdx.x & 63;
    const int t0   = (blockIdx.x * 4 + wave) * 4;  // first of this wave's 4 tokens

    // One 16B broadcast load each for 4 ids / 4 route indices.
    const i32x4 ids = *reinterpret_cast<const i32x4*>(input_ids + t0);
    const i32x4 wis = *reinterpret_cast<const i32x4*>(weight_indices + t0);

    const f32x4* __restrict__ s4[4];
#pragma unroll
    for (int k = 0; k < 4; ++k) {
        const int id = ids[k];
        const int wi = wis[k];
        const float* src = (wi < 0)
            ? base_weight + (size_t)id * kEmbedDim
            : delta_weights + ((size_t)wi * kVocab + (size_t)id) * kEmbedDim;
        s4[k] = reinterpret_cast<const f32x4*>(src);
    }

    // Issue all 16 loads before any store (compile-time indices only).
    f32x4 v[4][4];
#pragma unroll
    for (int k = 0; k < 4; ++k)
#pragma unroll
        for (int j = 0; j < 4; ++j)
            v[k][j] = s4[k][lane + 64 * j];

#pragma unroll
    for (int k = 0; k < 4; ++k) {
        f32x4* __restrict__ o4 =
            reinterpret_cast<f32x4*>(out + (size_t)(t0 + k) * kEmbedDim);
#pragma unroll
        for (int j = 0; j < 4; ++j)
            __builtin_nontemporal_store(v[k][j], &o4[lane + 64 * j]);
    }
}

extern "C" void kernel_launch(void* const* d_in, const int* in_sizes, int n_in,
                              void* d_out, int out_size, void* d_ws, size_t ws_size,
                              hipStream_t stream) {
    const int*   input_ids      = (const int*)d_in[0];
    const int*   weight_indices = (const int*)d_in[1];
    const float* base_weight    = (const float*)d_in[2];
    const float* delta_weights  = (const float*)d_in[3];
    float*       out            = (float*)d_out;

    const int num_tokens = in_sizes[0];  // 8192, divisible by 16
    const int grid       = num_tokens / 16;

    routed_embed_kernel<<<grid, 256, 0, stream>>>(
        input_ids, weight_indices, base_weight, delta_weights, out);
}